// Round 1
// 558.695 us; speedup vs baseline: 1.0168x; 1.0168x over previous
//
#include <hip/hip_runtime.h>
#include <math.h>

// Problem: B=8, S=512, V=32000, M=32, PAD_ID=1
// logp[b,s] = logits[b,s,a[b,s]] - logsumexp_{m: mask[b,s,m]>0}(logits[b,s,mask[b,s,m]])
// out[b] = sum_s logp[b,s] * (a[b,s] != 1)
// Softmax Z cancels in p_a/base -> no need to read the V dimension.
//
// This revision: consolidate launches (memset node replaces init kernel),
// 16 waves/block so block count and same-line atomic count drop 1024 -> 256.
// Per-wave numerics identical to previous (absmax 0.0) version.

#define BB 8
#define SS 512
#define VV 32000
#define MM 32

#define WAVES_PER_BLOCK 16
#define THREADS (WAVES_PER_BLOCK * 64)

__global__ __launch_bounds__(THREADS) void logp_kernel(
    const float* __restrict__ logits,   // [B*S, V]
    const int*   __restrict__ a,        // [B*S]
    const int*   __restrict__ mask,     // [B*S, M]
    float*       __restrict__ out)      // [B]
{
    const int wave = threadIdx.x >> 6;                      // 0..15
    const int lane = threadIdx.x & 63;
    const int pos  = blockIdx.x * WAVES_PER_BLOCK + wave;   // 0..B*S-1
    const int b    = pos >> 9;                              // pos / 512

    const float* __restrict__ row = logits + (size_t)pos * VV;

    // Independent loads first (a, mask), then both dependent gathers —
    // two parallel 1-deep chains, ~2 HBM latencies total per wave.
    const int aid = a[pos];

    // Lanes 0..31 gather masked logits; invalid/inactive lanes contribute
    // -inf to the max and 0 to the sum.
    float x = -INFINITY;
    if (lane < MM) {
        const int m = mask[pos * MM + lane];
        if (m > 0) x = row[m];
    }
    const float logit_a = row[aid];

    // Wave max (64-lane butterfly; lanes >=32 hold -inf).
    float mx = x;
    #pragma unroll
    for (int off = 32; off; off >>= 1)
        mx = fmaxf(mx, __shfl_xor(mx, off, 64));

    // Wave sum of exp(x - mx).
    float e = (x == -INFINITY) ? 0.0f : expf(x - mx);
    #pragma unroll
    for (int off = 32; off; off >>= 1)
        e += __shfl_xor(e, off, 64);

    const float lse  = mx + logf(e);
    const float logp = (aid != 1) ? (logit_a - lse) : 0.0f;

    // 16 waves per block, all same b (512 % 16 == 0): LDS reduce, ONE atomic
    // per block -> 256 same-line atomics total (was 1024).
    __shared__ float ws[WAVES_PER_BLOCK];
    if (lane == 0) ws[wave] = logp;
    __syncthreads();
    if (threadIdx.x == 0) {
        float s = 0.0f;
        #pragma unroll
        for (int i = 0; i < WAVES_PER_BLOCK; ++i) s += ws[i];
        atomicAdd(&out[b], s);
    }
}

extern "C" void kernel_launch(void* const* d_in, const int* in_sizes, int n_in,
                              void* d_out, int out_size, void* d_ws, size_t ws_size,
                              hipStream_t stream) {
    const float* logits = (const float*)d_in[0];
    const int*   a      = (const int*)d_in[1];
    const int*   mask   = (const int*)d_in[2];
    float*       out    = (float*)d_out;

    // Graph-capturable memset node (32 B) instead of a kernel launch.
    hipMemsetAsync(out, 0, BB * sizeof(float), stream);

    const int n_pos  = BB * SS;                  // 4096 positions
    const int blocks = n_pos / WAVES_PER_BLOCK;  // 256 blocks, 1/CU, 16 waves/CU
    logp_kernel<<<blocks, THREADS, 0, stream>>>(logits, a, mask, out);
}